// Round 1
// baseline (278.603 us; speedup 1.0000x reference)
//
#include <hip/hip_runtime.h>

// GRU: B=8192, T=1024, I=3, H=4, fp32.
// Layout: 1 block = 1 wave (64 threads) = 16 batches x 4 hidden units.
// lane = 4*b_local + j ; lane j owns hidden unit j of its batch.
// h exchange within the quad via DPP quad_perm rotates (full-rate VALU).
// x staged per 32-step chunk via coalesced float4 loads + LDS; out buffered
// in LDS, flushed as contiguous float4 runs per batch row.

#define TC 32
#define XS_STRIDE 99   // 96 data + 3 pad: conflict-free (3*b_l mod 32 distinct)
#define OS_STRIDE 132  // 128 data + 4 pad: 2-way max (free per m136)

template<int CTRL>
__device__ __forceinline__ float dpp_rot(float v) {
    int i = __builtin_bit_cast(int, v);
    int r = __builtin_amdgcn_mov_dpp(i, CTRL, 0xf, 0xf, true);
    return __builtin_bit_cast(float, r);
}

__device__ __forceinline__ float vrcp(float x) { return __builtin_amdgcn_rcpf(x); }

__device__ __forceinline__ float sigmoid_f(float x) {
    return vrcp(1.0f + __expf(-x));          // v_mul + v_exp + v_add + v_rcp
}
__device__ __forceinline__ float tanh_f(float x) {
    float e = __expf(2.0f * x);              // e^{2x}: +inf -> tanh=1, 0 -> -1, both exact
    return 1.0f - 2.0f * vrcp(e + 1.0f);
}

__global__ __launch_bounds__(64) void gru_kernel(
    const float* __restrict__ x,     // [B, T, 3]
    const float* __restrict__ w_ih,  // [12, 3]
    const float* __restrict__ w_hh,  // [12, 4]
    const float* __restrict__ b_ih,  // [12]
    const float* __restrict__ b_hh,  // [12]
    float* __restrict__ out)         // [B*T*4] then h_n [B*4]
{
    __shared__ float x_s[16 * XS_STRIDE];
    __shared__ float out_s[16 * OS_STRIDE];

    const int lane = threadIdx.x;
    const int bl   = lane >> 2;      // batch within block (0..15)
    const int j    = lane & 3;       // hidden unit (0..3)
    const int b0   = blockIdx.x * 16;

    // ---- per-lane constants (loaded once; L2/L3 broadcast) ----
    float wir[3], wiz[3], win[3];
    #pragma unroll
    for (int k = 0; k < 3; ++k) {
        wir[k] = w_ih[j * 3 + k];
        wiz[k] = w_ih[(4 + j) * 3 + k];
        win[k] = w_ih[(8 + j) * 3 + k];
    }
    // w_hh rows pre-permuted so index m multiplies h_{(j+m)&3} (DPP rotate order)
    float whr[4], whz[4], whn[4];
    #pragma unroll
    for (int m = 0; m < 4; ++m) {
        int k = (j + m) & 3;
        whr[m] = w_hh[j * 4 + k];
        whz[m] = w_hh[(4 + j) * 4 + k];
        whn[m] = w_hh[(8 + j) * 4 + k];
    }
    const float br  = b_ih[j]     + b_hh[j];       // foldable: r gate
    const float bz  = b_ih[4 + j] + b_hh[4 + j];   // foldable: z gate
    const float bin = b_ih[8 + j];                 // n gate input bias
    const float bhn = b_hh[8 + j];                 // n gate hidden bias (scaled by r)

    float h = 0.0f;

    // ---- x chunk prefetch: 16 batches x 96 floats = 384 float4, 6 per lane ----
    float4 xr[6];
    {
        #pragma unroll
        for (int u = 0; u < 6; ++u) {
            int f  = u * 64 + lane;
            int bb = f / 24;                 // 24 float4 per batch row
            int q  = f - bb * 24;
            xr[u] = *(const float4*)(x + (long long)(b0 + bb) * 3072 + q * 4);
        }
    }

    for (int c = 0; c < 32; ++c) {
        // stage prefetched regs -> LDS (scalar writes: stride 99 not 16B-aligned)
        #pragma unroll
        for (int u = 0; u < 6; ++u) {
            int f  = u * 64 + lane;
            int bb = f / 24;
            int q  = f - bb * 24;
            float* p = &x_s[bb * XS_STRIDE + q * 4];
            p[0] = xr[u].x; p[1] = xr[u].y; p[2] = xr[u].z; p[3] = xr[u].w;
        }
        __syncthreads();   // x_s ready; also fences last chunk's out_s flush vs new writes

        // kick off next chunk's global loads (overlap with compute below)
        if (c < 31) {
            int t0 = (c + 1) * TC;
            #pragma unroll
            for (int u = 0; u < 6; ++u) {
                int f  = u * 64 + lane;
                int bb = f / 24;
                int q  = f - bb * 24;
                xr[u] = *(const float4*)(x + (long long)(b0 + bb) * 3072 + t0 * 3 + q * 4);
            }
        }

        // ---- 32 recurrence steps ----
        const float* xs = &x_s[bl * XS_STRIDE];
        float*       os = &out_s[bl * OS_STRIDE];
        #pragma unroll 8
        for (int t = 0; t < TC; ++t) {
            float x0 = xs[t * 3 + 0], x1 = xs[t * 3 + 1], x2 = xs[t * 3 + 2];
            float sr = fmaf(wir[0], x0, fmaf(wir[1], x1, fmaf(wir[2], x2, br)));
            float sz = fmaf(wiz[0], x0, fmaf(wiz[1], x1, fmaf(wiz[2], x2, bz)));
            float sn = fmaf(win[0], x0, fmaf(win[1], x1, fmaf(win[2], x2, bin)));

            float h1 = dpp_rot<0x39>(h);   // quad_perm [1,2,3,0]
            float h2 = dpp_rot<0x4E>(h);   // quad_perm [2,3,0,1]
            float h3 = dpp_rot<0x93>(h);   // quad_perm [3,0,1,2]

            float gr = fmaf(whr[0], h, fmaf(whr[1], h1, fmaf(whr[2], h2, whr[3] * h3)));
            float gz = fmaf(whz[0], h, fmaf(whz[1], h1, fmaf(whz[2], h2, whz[3] * h3)));
            float gn = fmaf(whn[0], h, fmaf(whn[1], h1, fmaf(whn[2], h2, whn[3] * h3)));

            float r = sigmoid_f(sr + gr);
            float z = sigmoid_f(sz + gz);
            float n = tanh_f(fmaf(r, gn + bhn, sn));
            h = fmaf(z, h - n, n);          // (1-z)*n + z*h

            os[t * 4 + j] = h;
        }
        __syncthreads();   // out_s complete; x_s reads done before next overwrite

        // ---- flush out chunk: 16 batches x 128 floats = 512 float4, 8 per lane ----
        int t0 = c * TC;
        #pragma unroll
        for (int u = 0; u < 8; ++u) {
            int f  = u * 64 + lane;
            int bb = f >> 5;                 // 32 float4 per batch row
            int q  = f & 31;
            float4 v = *(const float4*)&out_s[bb * OS_STRIDE + q * 4];  // 528B stride: 16B-aligned
            *(float4*)(out + (long long)(b0 + bb) * 4096 + t0 * 4 + q * 4) = v;
        }
    }

    // ---- h_n: out[B*T*H + b*4 + j] ----
    out[33554432LL + (long long)(b0 + bl) * 4 + j] = h;
}

extern "C" void kernel_launch(void* const* d_in, const int* in_sizes, int n_in,
                              void* d_out, int out_size, void* d_ws, size_t ws_size,
                              hipStream_t stream) {
    const float* x    = (const float*)d_in[0];
    const float* w_ih = (const float*)d_in[1];
    const float* w_hh = (const float*)d_in[2];
    const float* b_ih = (const float*)d_in[3];
    const float* b_hh = (const float*)d_in[4];
    float* out = (float*)d_out;

    dim3 grid(512), block(64);   // 512 blocks x 16 batches = 8192
    gru_kernel<<<grid, block, 0, stream>>>(x, w_ih, w_hh, b_ih, b_hh, out);
}